// Round 1
// baseline (879.707 us; speedup 1.0000x reference)
//
#include <hip/hip_runtime.h>
#include <math.h>

// Normmax (alpha=1.5) via bisection. Key facts:
//   inv_am1 = 1/(alpha-1) = 2  ->  p = relu(x - tau)^2
//   p^alpha = p^1.5          ->  f-sum uses relu(x - tau)^3
//   tau_m > max-1 for every iteration (tau_lo starts at max-1 and only rises,
//   dm > 0), so elements <= max-1 contribute EXACTLY zero to every f and to
//   the final p. We compact the (tiny) active set and bisect on it only.

#define D        2048
#define WPB      4      // waves (=rows) per block, independent, no barriers
#define CAP      256    // compaction capacity per row
#define NITER    50

__device__ __forceinline__ float wave_sum64(float v) {
#pragma unroll
    for (int m = 32; m >= 1; m >>= 1) v += __shfl_xor(v, m, 64);
    return v;   // butterfly: every lane ends with the full sum (wave-uniform)
}

__device__ __forceinline__ float wave_max64(float v) {
#pragma unroll
    for (int m = 32; m >= 1; m >>= 1) v = fmaxf(v, __shfl_xor(v, m, 64));
    return v;
}

__global__ __launch_bounds__(WPB * 64)
void normmax_kernel(const float* __restrict__ X, float* __restrict__ Y, int n_rows) {
    __shared__ float cbuf[WPB][CAP];
    __shared__ int   ccnt[WPB];

    const int wave = threadIdx.x >> 6;
    const int lane = threadIdx.x & 63;
    const long long row = (long long)blockIdx.x * WPB + wave;
    if (row >= n_rows) return;   // no barriers in kernel, early-out is safe

    const float4* xrow = (const float4*)(X + row * (long long)D);
    float4*       yrow = (float4*)(Y + row * (long long)D);

    // --- load full row into registers, coalesced: float4 index = c*64 + lane
    float4 v[8];
#pragma unroll
    for (int c = 0; c < 8; ++c) v[c] = xrow[c * 64 + lane];

    // --- row max
    float mx = -INFINITY;
#pragma unroll
    for (int c = 0; c < 8; ++c)
        mx = fmaxf(mx, fmaxf(fmaxf(v[c].x, v[c].y), fmaxf(v[c].z, v[c].w)));
    const float max_val = wave_max64(mx);

    float tau_lo = max_val - 1.0f;                              // 1^(alpha-1)
    const float tau_hi = max_val - 0.022097086912079608f;       // (1/2048)^0.5
    float dm = tau_hi - tau_lo;
    const float thr = tau_lo;     // exact cutoff: x <= thr can never contribute

    // --- compact active elements into LDS (per-wave counter; same-wave DS ops
    //     are processed in order, atomics keep compiler ordering too)
    if (lane == 0) atomicExch(&ccnt[wave], 0);
#pragma unroll
    for (int c = 0; c < 8; ++c) {
        const float xs[4] = {v[c].x, v[c].y, v[c].z, v[c].w};
#pragma unroll
        for (int j = 0; j < 4; ++j) {
            if (xs[j] > thr) {
                int p = atomicAdd(&ccnt[wave], 1);
                if (p < CAP) cbuf[wave][p] = xs[j];
            }
        }
    }
    const int n_act = atomicAdd(&ccnt[wave], 0);   // atomic read: ordered vs adds

    float tau = tau_lo;   // will hold the LAST tau_m (what the reference uses)
    if (n_act <= 64) {
        // common case (~99% of rows): one active value per lane
        const float a0 = (lane < n_act) ? cbuf[wave][lane] : -1.0e30f;
        for (int it = 0; it < NITER; ++it) {
            dm *= 0.5f;
            tau = tau_lo + dm;
            const float r = fmaxf(a0 - tau, 0.0f);
            const float f = wave_sum64(r * r * r);   // sum(p^alpha)
            if (f >= 1.0f) tau_lo = tau;             // f - 1 >= 0 (exact, Sterbenz)
        }
    } else if (n_act <= CAP) {
        float a[4];
#pragma unroll
        for (int c = 0; c < 4; ++c) {
            const int idx = c * 64 + lane;
            a[c] = (idx < n_act) ? cbuf[wave][idx] : -1.0e30f;
        }
        for (int it = 0; it < NITER; ++it) {
            dm *= 0.5f;
            tau = tau_lo + dm;
            float local = 0.0f;
#pragma unroll
            for (int c = 0; c < 4; ++c) {
                const float r = fmaxf(a[c] - tau, 0.0f);
                local = fmaf(r * r, r, local);
            }
            const float f = wave_sum64(local);
            if (f >= 1.0f) tau_lo = tau;
        }
    } else {
        // pathological fallback: bisect over the full row held in registers
        for (int it = 0; it < NITER; ++it) {
            dm *= 0.5f;
            tau = tau_lo + dm;
            float local = 0.0f;
#pragma unroll
            for (int c = 0; c < 8; ++c) {
                const float r0 = fmaxf(v[c].x - tau, 0.0f);
                const float r1 = fmaxf(v[c].y - tau, 0.0f);
                const float r2 = fmaxf(v[c].z - tau, 0.0f);
                const float r3 = fmaxf(v[c].w - tau, 0.0f);
                local = fmaf(r0 * r0, r0, local);
                local = fmaf(r1 * r1, r1, local);
                local = fmaf(r2 * r2, r2, local);
                local = fmaf(r3 * r3, r3, local);
            }
            const float f = wave_sum64(local);
            if (f >= 1.0f) tau_lo = tau;
        }
    }

    // --- epilogue: p = relu(x - tau)^2, out = p / sum(p). Inactive elems -> 0.
    float local = 0.0f;
    float4 o[8];
#pragma unroll
    for (int c = 0; c < 8; ++c) {
        const float r0 = fmaxf(v[c].x - tau, 0.0f);
        const float r1 = fmaxf(v[c].y - tau, 0.0f);
        const float r2 = fmaxf(v[c].z - tau, 0.0f);
        const float r3 = fmaxf(v[c].w - tau, 0.0f);
        o[c].x = r0 * r0; o[c].y = r1 * r1; o[c].z = r2 * r2; o[c].w = r3 * r3;
        local += (o[c].x + o[c].y) + (o[c].z + o[c].w);
    }
    const float s   = wave_sum64(local);
    const float inv = 1.0f / s;
#pragma unroll
    for (int c = 0; c < 8; ++c) {
        float4 t = o[c];
        t.x *= inv; t.y *= inv; t.z *= inv; t.w *= inv;
        yrow[c * 64 + lane] = t;
    }
}

extern "C" void kernel_launch(void* const* d_in, const int* in_sizes, int n_in,
                              void* d_out, int out_size, void* d_ws, size_t ws_size,
                              hipStream_t stream) {
    const float* X = (const float*)d_in[0];
    float*       Y = (float*)d_out;
    const int n_rows = in_sizes[0] / D;            // 2*16*2048 = 65536
    const int blocks = (n_rows + WPB - 1) / WPB;   // 16384
    normmax_kernel<<<blocks, WPB * 64, 0, stream>>>(X, Y, n_rows);
}

// Round 3
// 854.158 us; speedup vs baseline: 1.0299x; 1.0299x over previous
//
#include <hip/hip_runtime.h>
#include <math.h>

// Normmax (alpha=1.5) via bisection. Algebraic facts:
//   inv_am1 = 1/(alpha-1) = 2  ->  p = relu(x - tau)^2
//   p^alpha = p^1.5            ->  f-sum uses relu(x - tau)^3
//   Every probe tau_m > max-1 (tau_lo starts there and only rises, dm>0), so
//   elements <= max-1 contribute EXACTLY zero to every f and to the final p.
//   For N(0,1) rows with d=2048 the active set is ~10-60 elements.
// R2/R3: all cross-lane ops via DPP (VALU, ~6 cyc) instead of LDS swizzle
//   (~100+ cyc); ballot/mbcnt compaction instead of serialized LDS atomics;
//   recompute epilogue to drop o[8] regs; 40 iters (41..50 are provable
//   no-ops: dm_40 ~ 9e-13 << 0.5 ulp(tau), tau_lo+dm rounds to tau_lo).
// R3 fix: nontemporal store needs a clang ext_vector float4, not HIP's class.

#define D        2048
#define WPB      4      // waves (=rows) per block, independent, no barriers
#define CAP      256    // compaction capacity per row
#define NITER    40

typedef float vfloat4 __attribute__((ext_vector_type(4)));

// ---- DPP wave64 reductions (result uniform via readlane 63) ----
template <int CTRL>
__device__ __forceinline__ float dpp_zero(float x) {
    // invalid source lanes contribute 0 (old = 0)
    return __int_as_float(
        __builtin_amdgcn_update_dpp(0, __float_as_int(x), CTRL, 0xf, 0xf, false));
}
template <int CTRL>
__device__ __forceinline__ float dpp_self(float x) {
    // invalid source lanes contribute x itself (old = x) — safe for max
    int xi = __float_as_int(x);
    return __int_as_float(__builtin_amdgcn_update_dpp(xi, xi, CTRL, 0xf, 0xf, false));
}

__device__ __forceinline__ float wave_sum_dpp(float x) {
    x += dpp_zero<0x111>(x);   // row_shr:1
    x += dpp_zero<0x112>(x);   // row_shr:2
    x += dpp_zero<0x114>(x);   // row_shr:4
    x += dpp_zero<0x118>(x);   // row_shr:8  -> lane 15+16k holds row sum
    x += dpp_zero<0x142>(x);   // row_bcast:15
    x += dpp_zero<0x143>(x);   // row_bcast:31 -> lane 63 holds total
    return __int_as_float(__builtin_amdgcn_readlane(__float_as_int(x), 63));
}

__device__ __forceinline__ float wave_max_dpp(float x) {
    x = fmaxf(x, dpp_self<0x111>(x));
    x = fmaxf(x, dpp_self<0x112>(x));
    x = fmaxf(x, dpp_self<0x114>(x));
    x = fmaxf(x, dpp_self<0x118>(x));
    x = fmaxf(x, dpp_self<0x142>(x));
    x = fmaxf(x, dpp_self<0x143>(x));
    return __int_as_float(__builtin_amdgcn_readlane(__float_as_int(x), 63));
}

__global__ __launch_bounds__(WPB * 64)
void normmax_kernel(const float* __restrict__ X, float* __restrict__ Y, int n_rows) {
    __shared__ float cbuf[WPB][CAP];

    const int wave = threadIdx.x >> 6;
    const int lane = threadIdx.x & 63;
    const long long row = (long long)blockIdx.x * WPB + wave;
    if (row >= n_rows) return;   // no barriers in kernel, early-out is safe

    const vfloat4* xrow = (const vfloat4*)(X + row * (long long)D);
    vfloat4*       yrow = (vfloat4*)(Y + row * (long long)D);

    // --- load full row into registers, coalesced: float4 index = c*64 + lane
    vfloat4 v[8];
#pragma unroll
    for (int c = 0; c < 8; ++c) v[c] = xrow[c * 64 + lane];

    // --- row max (DPP)
    float mx = -INFINITY;
#pragma unroll
    for (int c = 0; c < 8; ++c)
        mx = fmaxf(mx, fmaxf(fmaxf(v[c].x, v[c].y), fmaxf(v[c].z, v[c].w)));
    const float max_val = wave_max_dpp(mx);

    float tau_lo = max_val - 1.0f;                              // 1^(alpha-1)
    const float tau_hi = max_val - 0.022097086912079608f;       // (1/2048)^0.5
    float dm = tau_hi - tau_lo;
    const float thr = tau_lo;     // exact cutoff: x <= thr never contributes

    // --- compact active elements into LDS via ballot + mbcnt prefix
    const unsigned long long lt_mask = (1ull << lane) - 1ull;
    int base = 0;
#pragma unroll
    for (int c = 0; c < 8; ++c) {
        const float xs[4] = {v[c].x, v[c].y, v[c].z, v[c].w};
#pragma unroll
        for (int j = 0; j < 4; ++j) {
            const bool act = xs[j] > thr;
            const unsigned long long m = __ballot(act);
            if (act) {
                const unsigned long long mlt = m & lt_mask;
                const int pos = base +
                    __builtin_amdgcn_mbcnt_hi((unsigned)(mlt >> 32),
                        __builtin_amdgcn_mbcnt_lo((unsigned)mlt, 0));
                if (pos < CAP) cbuf[wave][pos] = xs[j];
            }
            base += __popcll(m);   // wave-uniform
        }
    }
    const int n_act = base;
    __asm__ volatile("s_waitcnt lgkmcnt(0)" ::: "memory");  // LDS writes visible

    float tau = tau_lo;   // will hold the LAST tau_m (what the reference uses)
    if (n_act <= 64) {
        // common case (~all rows): one active value per lane
        const float a0 = (lane < n_act) ? cbuf[wave][lane] : -1.0e30f;
        for (int it = 0; it < NITER; ++it) {
            dm *= 0.5f;
            tau = tau_lo + dm;
            const float r = fmaxf(a0 - tau, 0.0f);
            const float f = wave_sum_dpp(r * r * r);   // sum(p^alpha)
            if (f >= 1.0f) tau_lo = tau;
        }
    } else if (n_act <= CAP) {
        float a[4];
#pragma unroll
        for (int c = 0; c < 4; ++c) {
            const int idx = c * 64 + lane;
            a[c] = (idx < n_act) ? cbuf[wave][idx] : -1.0e30f;
        }
        for (int it = 0; it < NITER; ++it) {
            dm *= 0.5f;
            tau = tau_lo + dm;
            float local = 0.0f;
#pragma unroll
            for (int c = 0; c < 4; ++c) {
                const float r = fmaxf(a[c] - tau, 0.0f);
                local = fmaf(r * r, r, local);
            }
            const float f = wave_sum_dpp(local);
            if (f >= 1.0f) tau_lo = tau;
        }
    } else {
        // pathological fallback: bisect over the full row held in registers
        for (int it = 0; it < NITER; ++it) {
            dm *= 0.5f;
            tau = tau_lo + dm;
            float local = 0.0f;
#pragma unroll
            for (int c = 0; c < 8; ++c) {
                const float r0 = fmaxf(v[c].x - tau, 0.0f);
                const float r1 = fmaxf(v[c].y - tau, 0.0f);
                const float r2 = fmaxf(v[c].z - tau, 0.0f);
                const float r3 = fmaxf(v[c].w - tau, 0.0f);
                local = fmaf(r0 * r0, r0, local);
                local = fmaf(r1 * r1, r1, local);
                local = fmaf(r2 * r2, r2, local);
                local = fmaf(r3 * r3, r3, local);
            }
            const float f = wave_sum_dpp(local);
            if (f >= 1.0f) tau_lo = tau;
        }
    }

    // --- epilogue: p = relu(x - tau)^2, out = p / sum(p). Two passes over v
    //     (recompute r at store time) to keep VGPR pressure low.
    float local = 0.0f;
#pragma unroll
    for (int c = 0; c < 8; ++c) {
        const float r0 = fmaxf(v[c].x - tau, 0.0f);
        const float r1 = fmaxf(v[c].y - tau, 0.0f);
        const float r2 = fmaxf(v[c].z - tau, 0.0f);
        const float r3 = fmaxf(v[c].w - tau, 0.0f);
        local = fmaf(r0, r0, local);
        local = fmaf(r1, r1, local);
        local = fmaf(r2, r2, local);
        local = fmaf(r3, r3, local);
    }
    const float s   = wave_sum_dpp(local);
    const float inv = 1.0f / s;
#pragma unroll
    for (int c = 0; c < 8; ++c) {
        const float r0 = fmaxf(v[c].x - tau, 0.0f);
        const float r1 = fmaxf(v[c].y - tau, 0.0f);
        const float r2 = fmaxf(v[c].z - tau, 0.0f);
        const float r3 = fmaxf(v[c].w - tau, 0.0f);
        vfloat4 t;
        t.x = r0 * r0 * inv;
        t.y = r1 * r1 * inv;
        t.z = r2 * r2 * inv;
        t.w = r3 * r3 * inv;
        __builtin_nontemporal_store(t, &yrow[c * 64 + lane]);
    }
}

extern "C" void kernel_launch(void* const* d_in, const int* in_sizes, int n_in,
                              void* d_out, int out_size, void* d_ws, size_t ws_size,
                              hipStream_t stream) {
    const float* X = (const float*)d_in[0];
    float*       Y = (float*)d_out;
    const int n_rows = in_sizes[0] / D;            // 2*16*2048 = 65536
    const int blocks = (n_rows + WPB - 1) / WPB;   // 16384
    normmax_kernel<<<blocks, WPB * 64, 0, stream>>>(X, Y, n_rows);
}